// Round 1
// baseline (1118.803 us; speedup 1.0000x reference)
//
#include <hip/hip_runtime.h>
#include <hip/hip_bf16.h>

#define BB 4
#define CC 32
#define WW 256
#define HH 256
#define KK 9
#define WH (WW*HH)

// ---------------- K0: init stats + transpose w_dsc -> wdT[k][c][o] ----------------
__global__ void k0_init(const float* __restrict__ w_dsc, float* __restrict__ wdT,
                        float* __restrict__ stats1, float* __restrict__ stats2) {
    int i = blockIdx.x * 256 + threadIdx.x;
    if (i < 9216) {
        int k = i >> 10;          // 0..8
        int c = (i >> 5) & 31;
        int o = i & 31;
        wdT[i] = w_dsc[(o * 32 + c) * 9 + k];
    }
    if (i < 40) stats1[i] = 0.f;
    if (i < 64) stats2[i] = 0.f;
}

// ---------------- K1: 3x3 SAME conv, 10 output channels, + GN1 partial stats ------
__global__ __launch_bounds__(256) void k1_conv(
    const float* __restrict__ x, const float* __restrict__ w_off,
    const float* __restrict__ b_off, float* __restrict__ off_buf,
    float* __restrict__ stats1) {
    const int b = blockIdx.y;
    const int w = blockIdx.x;
    const int h = threadIdx.x;

    float acc[10];
#pragma unroll
    for (int oc = 0; oc < 10; ++oc) acc[oc] = b_off[oc];

    const float* xb = x + (size_t)b * CC * WH;
    for (int ic = 0; ic < CC; ++ic) {
        const float* pc = xb + (size_t)ic * WH;
        float v[9];
#pragma unroll
        for (int dy = 0; dy < 3; ++dy) {
            int ww = w + dy - 1;
#pragma unroll
            for (int dx = 0; dx < 3; ++dx) {
                int hh = h + dx - 1;
                bool ok = (ww >= 0) && (ww < WW) && (hh >= 0) && (hh < HH);
                v[dy * 3 + dx] = ok ? pc[ww * HH + hh] : 0.f;
            }
        }
        const float* wo = w_off + ic * 9;
#pragma unroll
        for (int oc = 0; oc < 10; ++oc) {
            const float* wp = wo + oc * (CC * 9);   // w_off[(oc*32+ic)*9 + j]
#pragma unroll
            for (int j = 0; j < 9; ++j) acc[oc] = fmaf(v[j], wp[j], acc[oc]);
        }
    }

    size_t base = (size_t)b * 10 * WH + (size_t)w * HH + h;
#pragma unroll
    for (int oc = 0; oc < 10; ++oc) off_buf[base + (size_t)oc * WH] = acc[oc];

    // GN1 partial stats: groups g=0..4 cover channels {2g,2g+1}
#pragma unroll
    for (int g = 0; g < 5; ++g) {
        float s = acc[2 * g] + acc[2 * g + 1];
        float q = acc[2 * g] * acc[2 * g] + acc[2 * g + 1] * acc[2 * g + 1];
#pragma unroll
        for (int m = 32; m > 0; m >>= 1) {
            s += __shfl_xor(s, m, 64);
            q += __shfl_xor(q, m, 64);
        }
        if ((h & 63) == 0) {
            atomicAdd(&stats1[(b * 5 + g) * 2 + 0], s);
            atomicAdd(&stats1[(b * 5 + g) * 2 + 1], q);
        }
    }
}

// ---------------- K2: finalize GN1 stats -> (mean, istd) --------------------------
__global__ void k2_fin1(const float* __restrict__ stats1, float* __restrict__ s1f) {
    int i = threadIdx.x;
    if (i < 20) {
        const float n = 2.f * WH;
        float s = stats1[2 * i], q = stats1[2 * i + 1];
        float m = s / n;
        float var = q / n - m * m;
        s1f[2 * i] = m;
        s1f[2 * i + 1] = rsqrtf(var + 1e-5f);
    }
}

// ---------------- K3: GN1+tanh+cumsum+bilinear sample + stride-9 conv + stats2 ----
__global__ __launch_bounds__(256) void k3_sample(
    const float* __restrict__ xin, const float* __restrict__ off_buf,
    const float* __restrict__ s1f, const float* __restrict__ go_scale,
    const float* __restrict__ go_bias, const float* __restrict__ wdT,
    const float* __restrict__ b_dsc, float* __restrict__ pre_out,
    float* __restrict__ stats2) {
    const int b = blockIdx.y;
    const int w = blockIdx.x;
    const int h = threadIdx.x;

    // offsets: GN1 + tanh on channels 0..8
    float t9[9];
    size_t obase = (size_t)b * 10 * WH + (size_t)w * HH + h;
#pragma unroll
    for (int c = 0; c < 9; ++c) {
        float v = off_buf[obase + (size_t)c * WH];
        int g = c >> 1;
        float mean = s1f[(b * 5 + g) * 2 + 0];
        float istd = s1f[(b * 5 + g) * 2 + 1];
        v = (v - mean) * istd * go_scale[c] + go_bias[c];
        t9[c] = tanhf(v);
    }
    // cumsum: ycum[k] = sum_{j=k..3} t9[j] (k<4); 0 (k=4); sum_{j=5..k} t9[j] (k>4)
    float ycum[9];
    ycum[3] = t9[3];
    ycum[2] = ycum[3] + t9[2];
    ycum[1] = ycum[2] + t9[1];
    ycum[0] = ycum[1] + t9[0];
    ycum[4] = 0.f;
    ycum[5] = t9[5];
    ycum[6] = ycum[5] + t9[6];
    ycum[7] = ycum[6] + t9[7];
    ycum[8] = ycum[7] + t9[8];

    float acc[32];
#pragma unroll
    for (int o = 0; o < 32; ++o) acc[o] = 0.f;

    const float* xb = xin + (size_t)b * CC * WH;

    for (int k = 0; k < 9; ++k) {
        float y_new = (float)w + ycum[k];
        float gy = y_new * (2.0f / (float)WW) - 1.f;
        gy = fminf(fmaxf(gy, -1.f), 1.f);
        float py = (gy + 1.f) * 0.5f * (float)(WW - 1);
        float xnw = (float)(h + k - 4);
        float gx = xnw * (2.0f / (float)HH) - 1.f;
        gx = fminf(fmaxf(gx, -1.f), 1.f);
        float px = (gx + 1.f) * 0.5f * (float)(HH - 1);

        float y0f = floorf(py), x0f = floorf(px);
        float wy = py - y0f, wx = px - x0f;
        int y0 = (int)fminf(fmaxf(y0f, 0.f), 255.f);
        int y1 = (int)fminf(fmaxf(y0f + 1.f, 0.f), 255.f);
        int x0 = (int)fminf(fmaxf(x0f, 0.f), 255.f);
        int x1 = (int)fminf(fmaxf(x0f + 1.f, 0.f), 255.f);
        float w00 = (1.f - wy) * (1.f - wx);
        float w01 = (1.f - wy) * wx;
        float w10 = wy * (1.f - wx);
        float w11 = wy * wx;
        int o00 = y0 * HH + x0, o01 = y0 * HH + x1;
        int o10 = y1 * HH + x0, o11 = y1 * HH + x1;

        const float* wk = wdT + k * 1024;
        for (int c = 0; c < CC; ++c) {
            const float* p = xb + (size_t)c * WH;
            float v = w00 * p[o00] + w01 * p[o01] + w10 * p[o10] + w11 * p[o11];
            const float4* wr4 = (const float4*)(wk + c * 32);
#pragma unroll
            for (int q = 0; q < 8; ++q) {
                float4 wv = wr4[q];
                acc[q * 4 + 0] = fmaf(v, wv.x, acc[q * 4 + 0]);
                acc[q * 4 + 1] = fmaf(v, wv.y, acc[q * 4 + 1]);
                acc[q * 4 + 2] = fmaf(v, wv.z, acc[q * 4 + 2]);
                acc[q * 4 + 3] = fmaf(v, wv.w, acc[q * 4 + 3]);
            }
        }
    }

    size_t pbase = (size_t)b * CC * WH + (size_t)w * HH + h;
#pragma unroll
    for (int o = 0; o < 32; ++o) {
        acc[o] += b_dsc[o];
        pre_out[pbase + (size_t)o * WH] = acc[o];
    }

    // GN2 partial stats: groups g=0..7 cover channels {4g..4g+3}
#pragma unroll
    for (int g = 0; g < 8; ++g) {
        float s = acc[4 * g] + acc[4 * g + 1] + acc[4 * g + 2] + acc[4 * g + 3];
        float q = acc[4 * g] * acc[4 * g] + acc[4 * g + 1] * acc[4 * g + 1] +
                  acc[4 * g + 2] * acc[4 * g + 2] + acc[4 * g + 3] * acc[4 * g + 3];
#pragma unroll
        for (int m = 32; m > 0; m >>= 1) {
            s += __shfl_xor(s, m, 64);
            q += __shfl_xor(q, m, 64);
        }
        if ((h & 63) == 0) {
            atomicAdd(&stats2[(b * 8 + g) * 2 + 0], s);
            atomicAdd(&stats2[(b * 8 + g) * 2 + 1], q);
        }
    }
}

// ---------------- K4: finalize GN2 stats ------------------------------------------
__global__ void k4_fin2(const float* __restrict__ stats2, float* __restrict__ s2f) {
    int i = threadIdx.x;
    if (i < 32) {
        const float n = 4.f * WH;
        float s = stats2[2 * i], q = stats2[2 * i + 1];
        float m = s / n;
        float var = q / n - m * m;
        s2f[2 * i] = m;
        s2f[2 * i + 1] = rsqrtf(var + 1e-5f);
    }
}

// ---------------- K5: GN2 apply + ReLU (in-place on d_out) ------------------------
__global__ __launch_bounds__(256) void k5_gn(float* __restrict__ out,
                                             const float* __restrict__ s2f,
                                             const float* __restrict__ gs,
                                             const float* __restrict__ gb) {
    size_t i = (size_t)blockIdx.x * 256 + threadIdx.x;  // < 8388608
    int bo = (int)(i >> 16);      // b*32 + o
    int b = bo >> 5;
    int o = bo & 31;
    int g = o >> 2;
    float mean = s2f[(b * 8 + g) * 2 + 0];
    float istd = s2f[(b * 8 + g) * 2 + 1];
    float v = out[i];
    v = (v - mean) * istd * gs[o] + gb[o];
    out[i] = fmaxf(v, 0.f);
}

extern "C" void kernel_launch(void* const* d_in, const int* in_sizes, int n_in,
                              void* d_out, int out_size, void* d_ws, size_t ws_size,
                              hipStream_t stream) {
    const float* x        = (const float*)d_in[0];
    const float* w_off    = (const float*)d_in[1];
    const float* b_off    = (const float*)d_in[2];
    const float* go_scale = (const float*)d_in[3];
    const float* go_bias  = (const float*)d_in[4];
    const float* w_dsc    = (const float*)d_in[5];
    const float* b_dsc    = (const float*)d_in[6];
    const float* gn_scale = (const float*)d_in[7];
    const float* gn_bias  = (const float*)d_in[8];
    float* out = (float*)d_out;

    float* ws      = (float*)d_ws;
    float* off_buf = ws;                        // 4*10*65536 = 2,621,440
    float* wdT     = off_buf + (size_t)BB * 10 * WH;  // 9216
    float* stats1  = wdT + 9216;                // 40
    float* s1f     = stats1 + 40;               // 40
    float* stats2  = s1f + 40;                  // 64
    float* s2f     = stats2 + 64;               // 64

    k0_init<<<36, 256, 0, stream>>>(w_dsc, wdT, stats1, stats2);
    k1_conv<<<dim3(WW, BB), 256, 0, stream>>>(x, w_off, b_off, off_buf, stats1);
    k2_fin1<<<1, 64, 0, stream>>>(stats1, s1f);
    k3_sample<<<dim3(WW, BB), 256, 0, stream>>>(x, off_buf, s1f, go_scale, go_bias,
                                                wdT, b_dsc, out, stats2);
    k4_fin2<<<1, 64, 0, stream>>>(stats2, s2f);
    k5_gn<<<(BB * CC * WH) / 256, 256, 0, stream>>>(out, s2f, gn_scale, gn_bias);
}

// Round 2
// 812.887 us; speedup vs baseline: 1.3763x; 1.3763x over previous
//
#include <hip/hip_runtime.h>
#include <hip/hip_bf16.h>

#define BB 4
#define CC 32
#define WW 256
#define HH 256
#define KK 9
#define WH (WW*HH)

// ---------------- K0: init stats + transpose w_dsc -> wdT[k][c][o] ----------------
__global__ void k0_init(const float* __restrict__ w_dsc, float* __restrict__ wdT,
                        float* __restrict__ stats1, float* __restrict__ stats2) {
    int i = blockIdx.x * 256 + threadIdx.x;
    if (i < 9216) {
        int k = i >> 10;          // 0..8
        int c = (i >> 5) & 31;
        int o = i & 31;
        wdT[i] = w_dsc[(o * 32 + c) * 9 + k];
    }
    if (i < 40) stats1[i] = 0.f;
    if (i < 64) stats2[i] = 0.f;
}

// ---------------- K1: 3x3 SAME conv (10 oc) via LDS tiles + GN1 stats -------------
// Block: (b, group of 4 w-rows), 1024 threads. LDS: 8ch x 6rows x 260cols.
__global__ __launch_bounds__(1024, 4) void k1_conv(
    const float* __restrict__ x, const float* __restrict__ w_off,
    const float* __restrict__ b_off, float* __restrict__ off_buf,
    float* __restrict__ stats1) {
    __shared__ float tile[8 * 6 * 260];   // 49,920 B

    const int b = blockIdx.y;
    const int w0 = blockIdx.x * 4;
    const int wi = threadIdx.x >> 8;
    const int h = threadIdx.x & 255;
    const int w = w0 + wi;

    float acc[10];
#pragma unroll
    for (int oc = 0; oc < 10; ++oc) acc[oc] = b_off[oc];

    const float* xb = x + (size_t)b * CC * WH;

    for (int cc0 = 0; cc0 < 32; cc0 += 8) {
        // stage 8 channels x 6 rows (w0-1 .. w0+4), zero-padded rows/cols
        for (int t = threadIdx.x; t < 8 * 6 * 256; t += 1024) {
            int c = t / 1536;            // 6*256
            int rem = t - c * 1536;
            int r = rem >> 8;
            int col = rem & 255;
            int y = w0 - 1 + r;
            float v = 0.f;
            if (y >= 0 && y < WW) v = xb[(size_t)(cc0 + c) * WH + y * HH + col];
            tile[(c * 6 + r) * 260 + 1 + col] = v;
        }
        if (threadIdx.x < 96) {
            int c = threadIdx.x / 12;
            int r = threadIdx.x - c * 12;
            int half = r >= 6;
            r -= half * 6;
            tile[(c * 6 + r) * 260 + (half ? 257 : 0)] = 0.f;
        }
        __syncthreads();

#pragma unroll
        for (int c = 0; c < 8; ++c) {
            float v[9];
#pragma unroll
            for (int dy = 0; dy < 3; ++dy) {
                const float* rp = tile + (c * 6 + wi + dy) * 260 + h;
#pragma unroll
                for (int dx = 0; dx < 3; ++dx) v[dy * 3 + dx] = rp[dx];
            }
            const float* wo = w_off + (cc0 + c) * 9;
#pragma unroll
            for (int oc = 0; oc < 10; ++oc) {
                const float* wp = wo + oc * (CC * 9);
#pragma unroll
                for (int j = 0; j < 9; ++j) acc[oc] = fmaf(v[j], wp[j], acc[oc]);
            }
        }
        __syncthreads();
    }

    size_t base = (size_t)b * 10 * WH + (size_t)w * HH + h;
#pragma unroll
    for (int oc = 0; oc < 10; ++oc) off_buf[base + (size_t)oc * WH] = acc[oc];

    // GN1 partial stats: groups g=0..4 cover channels {2g,2g+1}
#pragma unroll
    for (int g = 0; g < 5; ++g) {
        float s = acc[2 * g] + acc[2 * g + 1];
        float q = acc[2 * g] * acc[2 * g] + acc[2 * g + 1] * acc[2 * g + 1];
#pragma unroll
        for (int m = 32; m > 0; m >>= 1) {
            s += __shfl_xor(s, m, 64);
            q += __shfl_xor(q, m, 64);
        }
        if ((threadIdx.x & 63) == 0) {
            atomicAdd(&stats1[(b * 5 + g) * 2 + 0], s);
            atomicAdd(&stats1[(b * 5 + g) * 2 + 1], q);
        }
    }
}

// ---------------- K2: finalize GN1 stats -> (mean, istd) --------------------------
__global__ void k2_fin1(const float* __restrict__ stats1, float* __restrict__ s1f) {
    int i = threadIdx.x;
    if (i < 20) {
        const float n = 2.f * WH;
        float s = stats1[2 * i], q = stats1[2 * i + 1];
        float m = s / n;
        float var = q / n - m * m;
        s1f[2 * i] = m;
        s1f[2 * i + 1] = rsqrtf(var + 1e-5f);
    }
}

// ---------------- K3: GN1+tanh+cumsum + LDS-tiled bilinear + stride-9 conv --------
// Block: (b, group of 4 w-rows), 1024 threads. LDS: 4ch x 14rows x 260cols.
__global__ __launch_bounds__(1024, 4) void k3_sample(
    const float* __restrict__ xin, const float* __restrict__ off_buf,
    const float* __restrict__ s1f, const float* __restrict__ go_scale,
    const float* __restrict__ go_bias, const float* __restrict__ wdT,
    const float* __restrict__ b_dsc, float* __restrict__ pre_out,
    float* __restrict__ stats2) {
    __shared__ float tile[4 * 14 * 260];   // 58,240 B

    const int b = blockIdx.y;
    const int w0 = blockIdx.x * 4;
    const int wi = threadIdx.x >> 8;
    const int h = threadIdx.x & 255;
    const int w = w0 + wi;

    // offsets: GN1 + tanh on channels 0..8 -> cumsum
    float t9[9];
    size_t obase = (size_t)b * 10 * WH + (size_t)w * HH + h;
#pragma unroll
    for (int c = 0; c < 9; ++c) {
        float v = off_buf[obase + (size_t)c * WH];
        int g = c >> 1;
        float mean = s1f[(b * 5 + g) * 2 + 0];
        float istd = s1f[(b * 5 + g) * 2 + 1];
        v = (v - mean) * istd * go_scale[c] + go_bias[c];
        t9[c] = tanhf(v);
    }
    float ycum[9];
    ycum[3] = t9[3];
    ycum[2] = ycum[3] + t9[2];
    ycum[1] = ycum[2] + t9[1];
    ycum[0] = ycum[1] + t9[0];
    ycum[4] = 0.f;
    ycum[5] = t9[5];
    ycum[6] = ycum[5] + t9[6];
    ycum[7] = ycum[6] + t9[7];
    ycum[8] = ycum[7] + t9[8];

    float acc[32];
#pragma unroll
    for (int o = 0; o < 32; ++o) acc[o] = 0.f;

    const float* xb = xin + (size_t)b * CC * WH;
    const float SC = 255.f / 256.f;

    for (int cc0 = 0; cc0 < 32; cc0 += 4) {
        // stage 4 channels x 14 rows (w0-5 .. w0+8, clamped), float4 loads
        for (int t = threadIdx.x; t < 3584; t += 1024) {
            int c = t / 896;             // 14*64
            int rem = t - c * 896;
            int r = rem >> 6;
            int col4 = rem & 63;
            int y = w0 - 5 + r;
            y = min(max(y, 0), 255);
            const float4* src =
                (const float4*)(xb + (size_t)(cc0 + c) * WH + y * HH) + col4;
            *(float4*)(tile + (c * 14 + r) * 260 + (col4 << 2)) = *src;
        }
        if (threadIdx.x < 56) {
            int c = threadIdx.x / 14;
            int r = threadIdx.x - c * 14;
            tile[(c * 14 + r) * 260 + 256] = tile[(c * 14 + r) * 260 + 255];
        }
        __syncthreads();

        for (int k = 0; k < 9; ++k) {
            float py = fminf(fmaxf(((float)w + ycum[k]) * SC, 0.f), 255.f);
            float px = fminf(fmaxf((float)(h + k - 4) * SC, 0.f), 255.f);
            float y0f = floorf(py), x0f = floorf(px);
            float wy = py - y0f, wx = px - x0f;
            int r0 = (int)y0f - (w0 - 5);
            int r1 = min((int)y0f + 1, 255) - (w0 - 5);
            int x0 = (int)x0f;
            float w00 = (1.f - wy) * (1.f - wx);
            float w01 = (1.f - wy) * wx;
            float w10 = wy * (1.f - wx);
            float w11 = wy * wx;
            const float* wk = wdT + k * 1024 + cc0 * 32;
#pragma unroll
            for (int c = 0; c < 4; ++c) {
                const float* row0 = tile + (c * 14 + r0) * 260 + x0;
                const float* row1 = tile + (c * 14 + r1) * 260 + x0;
                float a00 = row0[0], a01 = row0[1];
                float a10 = row1[0], a11 = row1[1];
                float v = fmaf(w00, a00,
                          fmaf(w01, a01, fmaf(w10, a10, w11 * a11)));
                const float4* wr4 = (const float4*)(wk + c * 32);
#pragma unroll
                for (int q = 0; q < 8; ++q) {
                    float4 wv = wr4[q];
                    acc[q * 4 + 0] = fmaf(v, wv.x, acc[q * 4 + 0]);
                    acc[q * 4 + 1] = fmaf(v, wv.y, acc[q * 4 + 1]);
                    acc[q * 4 + 2] = fmaf(v, wv.z, acc[q * 4 + 2]);
                    acc[q * 4 + 3] = fmaf(v, wv.w, acc[q * 4 + 3]);
                }
            }
        }
        __syncthreads();
    }

    size_t pbase = (size_t)b * CC * WH + (size_t)w * HH + h;
#pragma unroll
    for (int o = 0; o < 32; ++o) {
        acc[o] += b_dsc[o];
        pre_out[pbase + (size_t)o * WH] = acc[o];
    }

    // GN2 partial stats: groups g=0..7 cover channels {4g..4g+3}
#pragma unroll
    for (int g = 0; g < 8; ++g) {
        float s = acc[4 * g] + acc[4 * g + 1] + acc[4 * g + 2] + acc[4 * g + 3];
        float q = acc[4 * g] * acc[4 * g] + acc[4 * g + 1] * acc[4 * g + 1] +
                  acc[4 * g + 2] * acc[4 * g + 2] + acc[4 * g + 3] * acc[4 * g + 3];
#pragma unroll
        for (int m = 32; m > 0; m >>= 1) {
            s += __shfl_xor(s, m, 64);
            q += __shfl_xor(q, m, 64);
        }
        if ((threadIdx.x & 63) == 0) {
            atomicAdd(&stats2[(b * 8 + g) * 2 + 0], s);
            atomicAdd(&stats2[(b * 8 + g) * 2 + 1], q);
        }
    }
}

// ---------------- K4: finalize GN2 stats ------------------------------------------
__global__ void k4_fin2(const float* __restrict__ stats2, float* __restrict__ s2f) {
    int i = threadIdx.x;
    if (i < 32) {
        const float n = 4.f * WH;
        float s = stats2[2 * i], q = stats2[2 * i + 1];
        float m = s / n;
        float var = q / n - m * m;
        s2f[2 * i] = m;
        s2f[2 * i + 1] = rsqrtf(var + 1e-5f);
    }
}

// ---------------- K5: GN2 apply + ReLU (in-place on d_out) ------------------------
__global__ __launch_bounds__(256) void k5_gn(float* __restrict__ out,
                                             const float* __restrict__ s2f,
                                             const float* __restrict__ gs,
                                             const float* __restrict__ gb) {
    size_t i = (size_t)blockIdx.x * 256 + threadIdx.x;  // < 8388608
    int bo = (int)(i >> 16);      // b*32 + o
    int b = bo >> 5;
    int o = bo & 31;
    int g = o >> 2;
    float mean = s2f[(b * 8 + g) * 2 + 0];
    float istd = s2f[(b * 8 + g) * 2 + 1];
    float v = out[i];
    v = (v - mean) * istd * gs[o] + gb[o];
    out[i] = fmaxf(v, 0.f);
}

extern "C" void kernel_launch(void* const* d_in, const int* in_sizes, int n_in,
                              void* d_out, int out_size, void* d_ws, size_t ws_size,
                              hipStream_t stream) {
    const float* x        = (const float*)d_in[0];
    const float* w_off    = (const float*)d_in[1];
    const float* b_off    = (const float*)d_in[2];
    const float* go_scale = (const float*)d_in[3];
    const float* go_bias  = (const float*)d_in[4];
    const float* w_dsc    = (const float*)d_in[5];
    const float* b_dsc    = (const float*)d_in[6];
    const float* gn_scale = (const float*)d_in[7];
    const float* gn_bias  = (const float*)d_in[8];
    float* out = (float*)d_out;

    float* ws      = (float*)d_ws;
    float* off_buf = ws;                              // 4*10*65536
    float* wdT     = off_buf + (size_t)BB * 10 * WH;  // 9216
    float* stats1  = wdT + 9216;                      // 40
    float* s1f     = stats1 + 40;                     // 40
    float* stats2  = s1f + 40;                        // 64
    float* s2f     = stats2 + 64;                     // 64

    k0_init<<<36, 256, 0, stream>>>(w_dsc, wdT, stats1, stats2);
    k1_conv<<<dim3(64, BB), 1024, 0, stream>>>(x, w_off, b_off, off_buf, stats1);
    k2_fin1<<<1, 64, 0, stream>>>(stats1, s1f);
    k3_sample<<<dim3(64, BB), 1024, 0, stream>>>(x, off_buf, s1f, go_scale, go_bias,
                                                 wdT, b_dsc, out, stats2);
    k4_fin2<<<1, 64, 0, stream>>>(stats2, s2f);
    k5_gn<<<(BB * CC * WH) / 256, 256, 0, stream>>>(out, s2f, gn_scale, gn_bias);
}

// Round 3
// 315.985 us; speedup vs baseline: 3.5407x; 2.5725x over previous
//
#include <hip/hip_runtime.h>
#include <hip/hip_bf16.h>

#define BB 4
#define CC 32
#define WW 256
#define HH 256
#define KK 9
#define WH (WW*HH)

// ---------------- K0: init stats + build weight layouts ---------------------------
// wT1[ic][oc][12]   : k1 weights, 9 taps padded to 12 for float4 access (3840 f)
// wdT2[((ch*9+k)*4+cl)*32 + o] : k3 weights in exact inner-loop traversal order
__global__ void k0_init(const float* __restrict__ w_dsc, const float* __restrict__ w_off,
                        float* __restrict__ wT1, float* __restrict__ wdT2,
                        float* __restrict__ stats1, float* __restrict__ stats2) {
    int i = blockIdx.x * 256 + threadIdx.x;
    if (i < 9216) {
        int o = i & 31;
        int t = i >> 5;           // ((ch*9)+k)*4+cl
        int cl = t & 3;
        int t2 = t >> 2;
        int k = t2 % 9;
        int ch = t2 / 9;
        int c = ch * 4 + cl;
        wdT2[i] = w_dsc[(o * 32 + c) * 9 + k];
    }
    if (i < 3840) {
        int j = i % 12;
        int t = i / 12;
        int oc = t % 10;
        int ic = t / 10;
        wT1[i] = (j < 9) ? w_off[(oc * 32 + ic) * 9 + j] : 0.f;
    }
    if (i < 40) stats1[i] = 0.f;
    if (i < 64) stats2[i] = 0.f;
}

// ---------------- K1: 3x3 SAME conv (10 oc), P=2 pixels/thread --------------------
// Block: (b, w-pair), 256 threads. LDS: 8ch x 4rows x 260.
__global__ __launch_bounds__(256) void k1_conv(
    const float* __restrict__ x, const float* __restrict__ wT1,
    const float* __restrict__ b_off, float* __restrict__ off_buf,
    float* __restrict__ stats1) {
    __shared__ float tile[8 * 4 * 260];   // 33,280 B

    const int b = blockIdx.y;
    const int w0 = blockIdx.x * 2;
    const int h = threadIdx.x;

    float acc0[10], acc1[10];
#pragma unroll
    for (int oc = 0; oc < 10; ++oc) { acc0[oc] = b_off[oc]; acc1[oc] = b_off[oc]; }

    const float* xb = x + (size_t)b * CC * WH;

    for (int ck = 0; ck < 4; ++ck) {
        for (int t = threadIdx.x; t < 8192; t += 256) {
            int c = t >> 10;
            int rem = t & 1023;
            int r = rem >> 8;
            int col = rem & 255;
            int y = w0 - 1 + r;
            float v = (y >= 0 && y < 256) ? xb[(size_t)(ck * 8 + c) * WH + y * 256 + col] : 0.f;
            tile[(c * 4 + r) * 260 + 1 + col] = v;
        }
        if (threadIdx.x < 64) {
            int c = threadIdx.x >> 3;
            int idx = threadIdx.x & 7;
            int r = idx >> 1;
            int side = idx & 1;
            tile[(c * 4 + r) * 260 + (side ? 257 : 0)] = 0.f;
        }
        __syncthreads();

#pragma unroll
        for (int c = 0; c < 8; ++c) {
            float v[12];
#pragma unroll
            for (int r = 0; r < 4; ++r)
#pragma unroll
                for (int dx = 0; dx < 3; ++dx)
                    v[r * 3 + dx] = tile[(c * 4 + r) * 260 + h + dx];

            const float* wp = wT1 + (size_t)(ck * 8 + c) * 120;
#pragma unroll
            for (int oc = 0; oc < 10; ++oc) {
                float4 A = *(const float4*)(wp + oc * 12);
                float4 Bv = *(const float4*)(wp + oc * 12 + 4);
                float w8 = wp[oc * 12 + 8];
                float s0 = fmaf(v[0], A.x, fmaf(v[1], A.y, fmaf(v[2], A.z,
                           fmaf(v[3], A.w, fmaf(v[4], Bv.x, fmaf(v[5], Bv.y,
                           fmaf(v[6], Bv.z, fmaf(v[7], Bv.w, v[8] * w8))))))));
                float s1 = fmaf(v[3], A.x, fmaf(v[4], A.y, fmaf(v[5], A.z,
                           fmaf(v[6], A.w, fmaf(v[7], Bv.x, fmaf(v[8], Bv.y,
                           fmaf(v[9], Bv.z, fmaf(v[10], Bv.w, v[11] * w8))))))));
                acc0[oc] += s0;
                acc1[oc] += s1;
            }
        }
        __syncthreads();
    }

#pragma unroll
    for (int oc = 0; oc < 10; ++oc) {
        size_t base = ((size_t)b * 10 + oc) * WH + (size_t)w0 * 256 + h;
        off_buf[base] = acc0[oc];
        off_buf[base + 256] = acc1[oc];
    }

    // GN1 stats, block-reduced: groups g cover channels {2g,2g+1}
    const int lane = threadIdx.x & 63;
    const int wv = threadIdx.x >> 6;
    __syncthreads();   // tile reads done; reuse tile for reduction
#pragma unroll
    for (int g = 0; g < 5; ++g) {
        float s = acc0[2 * g] + acc0[2 * g + 1] + acc1[2 * g] + acc1[2 * g + 1];
        float q = acc0[2 * g] * acc0[2 * g] + acc0[2 * g + 1] * acc0[2 * g + 1] +
                  acc1[2 * g] * acc1[2 * g] + acc1[2 * g + 1] * acc1[2 * g + 1];
#pragma unroll
        for (int m = 32; m > 0; m >>= 1) {
            s += __shfl_xor(s, m, 64);
            q += __shfl_xor(q, m, 64);
        }
        if (lane == 0) {
            tile[(g * 2 + 0) * 4 + wv] = s;
            tile[(g * 2 + 1) * 4 + wv] = q;
        }
    }
    __syncthreads();
    if (threadIdx.x < 10) {
        int g = threadIdx.x >> 1;
        int which = threadIdx.x & 1;
        float sum = tile[(g * 2 + which) * 4 + 0] + tile[(g * 2 + which) * 4 + 1] +
                    tile[(g * 2 + which) * 4 + 2] + tile[(g * 2 + which) * 4 + 3];
        atomicAdd(&stats1[(b * 5 + g) * 2 + which], sum);
    }
}

// ---------------- K2: finalize GN1 stats -> (mean, istd) --------------------------
__global__ void k2_fin1(const float* __restrict__ stats1, float* __restrict__ s1f) {
    int i = threadIdx.x;
    if (i < 20) {
        const float n = 2.f * WH;
        float s = stats1[2 * i], q = stats1[2 * i + 1];
        float m = s / n;
        float var = q / n - m * m;
        s1f[2 * i] = m;
        s1f[2 * i + 1] = rsqrtf(var + 1e-5f);
    }
}

// ---------------- K3: GN1+tanh+cumsum + LDS bilinear + stride-9 conv --------------
// Block: (b, 4 w-rows, 64 h-cols), 256 threads = 256 px. LDS: 4ch x 14r x 76c.
// Weights streamed from linearized wdT2 with 1-deep register prefetch.
__global__ __launch_bounds__(256, 4) void k3_sample(
    const float* __restrict__ xin, const float* __restrict__ off_buf,
    const float* __restrict__ s1f, const float* __restrict__ go_scale,
    const float* __restrict__ go_bias, const float* __restrict__ wdT2,
    const float* __restrict__ b_dsc, float* __restrict__ pre_out,
    float* __restrict__ stats2) {
    __shared__ float tile[4 * 14 * 76];   // 17,024 B

    const int b = blockIdx.z;
    const int w0 = blockIdx.y * 4;
    const int h0 = blockIdx.x * 64;
    const int lane = threadIdx.x & 63;
    const int wv = threadIdx.x >> 6;      // wave id = w-row index
    const int h = h0 + lane;
    const int w = w0 + wv;
    const int row0 = w0 - 5;
    const int col0 = h0 - 8;

    // offsets: GN1 + tanh on channels 0..8 -> cumsum
    float t9[9];
    size_t obase = (size_t)b * 10 * WH + (size_t)w * 256 + h;
#pragma unroll
    for (int c = 0; c < 9; ++c) {
        float v = off_buf[obase + (size_t)c * WH];
        int g = c >> 1;
        float mean = s1f[(b * 5 + g) * 2 + 0];
        float istd = s1f[(b * 5 + g) * 2 + 1];
        v = (v - mean) * istd * go_scale[c] + go_bias[c];
        t9[c] = tanhf(v);
    }
    float ycum[9];
    ycum[3] = t9[3];
    ycum[2] = ycum[3] + t9[2];
    ycum[1] = ycum[2] + t9[1];
    ycum[0] = ycum[1] + t9[0];
    ycum[4] = 0.f;
    ycum[5] = t9[5];
    ycum[6] = ycum[5] + t9[6];
    ycum[7] = ycum[6] + t9[7];
    ycum[8] = ycum[7] + t9[8];

    float acc[32];
#pragma unroll
    for (int o = 0; o < 32; ++o) acc[o] = 0.f;

    const float* xb = xin + (size_t)b * CC * WH;
    const float SC = 255.f / 256.f;

    const float4* wp = (const float4*)wdT2;
    float4 wc[8];
#pragma unroll
    for (int q = 0; q < 8; ++q) wc[q] = wp[q];
    wp += 8;

    for (int ch = 0; ch < 8; ++ch) {
        // stage 4 channels x 14 rows x 76 cols (replicate-clamped)
        for (int t = threadIdx.x; t < 1064; t += 256) {
            int c = t / 266;              // 14*19
            int rem = t - c * 266;
            int r = rem / 19;
            int cf = rem - r * 19;
            int y = min(max(row0 + r, 0), 255);
            int g0 = col0 + (cf << 2);
            const float* src = xb + (size_t)(ch * 4 + c) * WH + y * 256;
            float4 val;
            if (g0 >= 0 && g0 <= 252) {
                val = *(const float4*)(src + g0);
            } else {
                val.x = src[min(max(g0, 0), 255)];
                val.y = src[min(max(g0 + 1, 0), 255)];
                val.z = src[min(max(g0 + 2, 0), 255)];
                val.w = src[min(max(g0 + 3, 0), 255)];
            }
            *(float4*)(tile + (c * 14 + r) * 76 + (cf << 2)) = val;
        }
        __syncthreads();

#pragma unroll
        for (int k = 0; k < 9; ++k) {
            float py = fminf(fmaxf(((float)w + ycum[k]) * SC, 0.f), 255.f);
            float pxc = fminf(fmaxf((float)(h + k - 4) * SC, 0.f), 255.f);
            float y0f = floorf(py), x0f = floorf(pxc);
            float wy = py - y0f, wx = pxc - x0f;
            int r0 = (int)y0f - row0;
            int r1 = min((int)y0f + 1, 255) - row0;
            int tc = (int)x0f - col0;
            float w00 = (1.f - wy) * (1.f - wx);
            float w01 = (1.f - wy) * wx;
            float w10 = wy * (1.f - wx);
            float w11 = wy * wx;
#pragma unroll
            for (int cl = 0; cl < 4; ++cl) {
                float4 wn[8];
#pragma unroll
                for (int q = 0; q < 8; ++q) wn[q] = wp[q];
                wp += 8;

                const float* p0 = tile + (cl * 14 + r0) * 76 + tc;
                const float* p1 = tile + (cl * 14 + r1) * 76 + tc;
                float v = fmaf(w00, p0[0],
                          fmaf(w01, p0[1], fmaf(w10, p1[0], w11 * p1[1])));
#pragma unroll
                for (int q = 0; q < 8; ++q) {
                    acc[q * 4 + 0] = fmaf(v, wc[q].x, acc[q * 4 + 0]);
                    acc[q * 4 + 1] = fmaf(v, wc[q].y, acc[q * 4 + 1]);
                    acc[q * 4 + 2] = fmaf(v, wc[q].z, acc[q * 4 + 2]);
                    acc[q * 4 + 3] = fmaf(v, wc[q].w, acc[q * 4 + 3]);
                }
#pragma unroll
                for (int q = 0; q < 8; ++q) wc[q] = wn[q];
            }
        }
        __syncthreads();
    }

    size_t pbase = (size_t)b * CC * WH + (size_t)w * 256 + h;
#pragma unroll
    for (int o = 0; o < 32; ++o) {
        acc[o] += b_dsc[o];
        pre_out[pbase + (size_t)o * WH] = acc[o];
    }

    // GN2 stats, block-reduced: groups g cover channels {4g..4g+3}
#pragma unroll
    for (int g = 0; g < 8; ++g) {
        float s = acc[4 * g] + acc[4 * g + 1] + acc[4 * g + 2] + acc[4 * g + 3];
        float q = acc[4 * g] * acc[4 * g] + acc[4 * g + 1] * acc[4 * g + 1] +
                  acc[4 * g + 2] * acc[4 * g + 2] + acc[4 * g + 3] * acc[4 * g + 3];
#pragma unroll
        for (int m = 32; m > 0; m >>= 1) {
            s += __shfl_xor(s, m, 64);
            q += __shfl_xor(q, m, 64);
        }
        if (lane == 0) {
            tile[(g * 2 + 0) * 4 + wv] = s;
            tile[(g * 2 + 1) * 4 + wv] = q;
        }
    }
    __syncthreads();
    if (threadIdx.x < 16) {
        int g = threadIdx.x >> 1;
        int which = threadIdx.x & 1;
        float sum = tile[(g * 2 + which) * 4 + 0] + tile[(g * 2 + which) * 4 + 1] +
                    tile[(g * 2 + which) * 4 + 2] + tile[(g * 2 + which) * 4 + 3];
        atomicAdd(&stats2[(b * 8 + g) * 2 + which], sum);
    }
}

// ---------------- K4: finalize GN2 stats ------------------------------------------
__global__ void k4_fin2(const float* __restrict__ stats2, float* __restrict__ s2f) {
    int i = threadIdx.x;
    if (i < 32) {
        const float n = 4.f * WH;
        float s = stats2[2 * i], q = stats2[2 * i + 1];
        float m = s / n;
        float var = q / n - m * m;
        s2f[2 * i] = m;
        s2f[2 * i + 1] = rsqrtf(var + 1e-5f);
    }
}

// ---------------- K5: GN2 apply + ReLU (in-place on d_out) ------------------------
__global__ __launch_bounds__(256) void k5_gn(float* __restrict__ out,
                                             const float* __restrict__ s2f,
                                             const float* __restrict__ gs,
                                             const float* __restrict__ gb) {
    size_t i = (size_t)blockIdx.x * 256 + threadIdx.x;  // < 8388608
    int bo = (int)(i >> 16);      // b*32 + o
    int b = bo >> 5;
    int o = bo & 31;
    int g = o >> 2;
    float mean = s2f[(b * 8 + g) * 2 + 0];
    float istd = s2f[(b * 8 + g) * 2 + 1];
    float v = out[i];
    v = (v - mean) * istd * gs[o] + gb[o];
    out[i] = fmaxf(v, 0.f);
}

extern "C" void kernel_launch(void* const* d_in, const int* in_sizes, int n_in,
                              void* d_out, int out_size, void* d_ws, size_t ws_size,
                              hipStream_t stream) {
    const float* x        = (const float*)d_in[0];
    const float* w_off    = (const float*)d_in[1];
    const float* b_off    = (const float*)d_in[2];
    const float* go_scale = (const float*)d_in[3];
    const float* go_bias  = (const float*)d_in[4];
    const float* w_dsc    = (const float*)d_in[5];
    const float* b_dsc    = (const float*)d_in[6];
    const float* gn_scale = (const float*)d_in[7];
    const float* gn_bias  = (const float*)d_in[8];
    float* out = (float*)d_out;

    float* ws      = (float*)d_ws;
    float* off_buf = ws;                              // 2,621,440
    float* wT1     = off_buf + (size_t)BB * 10 * WH;  // 3,840
    float* wdT2    = wT1 + 3840;                      // 9,216
    float* stats1  = wdT2 + 9216;                     // 40
    float* s1f     = stats1 + 40;                     // 40
    float* stats2  = s1f + 40;                        // 64
    float* s2f     = stats2 + 64;                     // 64

    k0_init<<<36, 256, 0, stream>>>(w_dsc, w_off, wT1, wdT2, stats1, stats2);
    k1_conv<<<dim3(128, BB), 256, 0, stream>>>(x, wT1, b_off, off_buf, stats1);
    k2_fin1<<<1, 64, 0, stream>>>(stats1, s1f);
    k3_sample<<<dim3(4, 64, BB), 256, 0, stream>>>(x, off_buf, s1f, go_scale, go_bias,
                                                   wdT2, b_dsc, out, stats2);
    k4_fin2<<<1, 64, 0, stream>>>(stats2, s2f);
    k5_gn<<<(BB * CC * WH) / 256, 256, 0, stream>>>(out, s2f, gn_scale, gn_bias);
}

// Round 4
// 309.790 us; speedup vs baseline: 3.6115x; 1.0200x over previous
//
#include <hip/hip_runtime.h>
#include <hip/hip_bf16.h>

#define BB 4
#define CC 32
#define WW 256
#define HH 256
#define KK 9
#define WH (WW*HH)

// ---------------- K0: init stats + build weight layouts ---------------------------
// wT1[ic][oc][12] (+16 zero pad): k1 weights, 9 taps padded to 12 -> float4 stream
// wdT2[((ch*9+k)*4+cl)*32 + o] (+32 zero pad): k3 weights in traversal order
__global__ void k0_init(const float* __restrict__ w_dsc, const float* __restrict__ w_off,
                        float* __restrict__ wT1, float* __restrict__ wdT2,
                        float* __restrict__ stats1, float* __restrict__ stats2) {
    int i = blockIdx.x * 256 + threadIdx.x;
    if (i < 9248) {
        float v = 0.f;
        if (i < 9216) {
            int o = i & 31;
            int t = i >> 5;           // ((ch*9)+k)*4+cl
            int cl = t & 3;
            int t2 = t >> 2;
            int k = t2 % 9;
            int ch = t2 / 9;
            int c = ch * 4 + cl;
            v = w_dsc[(o * 32 + c) * 9 + k];
        }
        wdT2[i] = v;
    }
    if (i < 3856) {
        float v = 0.f;
        if (i < 3840) {
            int j = i % 12;
            int t = i / 12;
            int oc = t % 10;
            int ic = t / 10;
            v = (j < 9) ? w_off[(oc * 32 + ic) * 9 + j] : 0.f;
        }
        wT1[i] = v;
    }
    if (i < 40) stats1[i] = 0.f;
    if (i < 64) stats2[i] = 0.f;
}

// ---------------- K1: 3x3 SAME conv (10 oc), 1 px/thread, streamed weights --------
// Block: (h-half, w-pair, b), 256 threads. LDS: 8ch x 4rows x 132.
__global__ __launch_bounds__(256) void k1_conv(
    const float* __restrict__ x, const float* __restrict__ wT1,
    const float* __restrict__ b_off, float* __restrict__ off_buf,
    float* __restrict__ stats1) {
    __shared__ float tile[8 * 4 * 132];   // 16,896 B

    const int b = blockIdx.z;
    const int w0 = blockIdx.y * 2;
    const int h0 = blockIdx.x * 128;
    const int hl = threadIdx.x & 127;
    const int wi = threadIdx.x >> 7;
    const int w = w0 + wi;
    const int h = h0 + hl;

    float acc[10];
#pragma unroll
    for (int oc = 0; oc < 10; ++oc) acc[oc] = b_off[oc];

    const float* xb = x + (size_t)b * CC * WH;

    const float4* wp = (const float4*)wT1;
    float4 cA = wp[0], cB = wp[1], cCq = wp[2];
    wp += 3;

    for (int ck = 0; ck < 4; ++ck) {
        // stage 8 ch x 4 rows (w0-1..w0+2) x 130 cols (h0-1..h0+128), zero-padded
        for (int t = threadIdx.x; t < 4160; t += 256) {
            int c = t / 520;
            int rem = t - c * 520;
            int r = rem / 130;
            int cl = rem - r * 130;
            int y = w0 - 1 + r;
            int g = h0 - 1 + cl;
            float v = 0.f;
            if (y >= 0 && y < 256 && g >= 0 && g < 256)
                v = xb[(size_t)(ck * 8 + c) * WH + y * 256 + g];
            tile[(c * 4 + r) * 132 + cl] = v;
        }
        __syncthreads();

#pragma unroll
        for (int c = 0; c < 8; ++c) {
            float v[9];
#pragma unroll
            for (int dy = 0; dy < 3; ++dy)
#pragma unroll
                for (int dx = 0; dx < 3; ++dx)
                    v[dy * 3 + dx] = tile[(c * 4 + wi + dy) * 132 + hl + dx];

#pragma unroll
            for (int oc = 0; oc < 10; ++oc) {
                float4 nA = wp[0], nB = wp[1], nC = wp[2];
                wp += 3;
                float s = fmaf(v[0], cA.x, fmaf(v[1], cA.y, fmaf(v[2], cA.z,
                          fmaf(v[3], cA.w, fmaf(v[4], cB.x, fmaf(v[5], cB.y,
                          fmaf(v[6], cB.z, fmaf(v[7], cB.w, v[8] * cCq.x))))))));
                acc[oc] += s;
                cA = nA; cB = nB; cCq = nC;
            }
        }
        __syncthreads();
    }

#pragma unroll
    for (int oc = 0; oc < 10; ++oc)
        off_buf[((size_t)b * 10 + oc) * WH + (size_t)w * 256 + h] = acc[oc];

    // GN1 stats, block-reduced: group g covers channels {2g,2g+1}
    const int lane = threadIdx.x & 63;
    const int wv = threadIdx.x >> 6;
    __syncthreads();   // done with tile; reuse for reduction
#pragma unroll
    for (int g = 0; g < 5; ++g) {
        float s = acc[2 * g] + acc[2 * g + 1];
        float q = acc[2 * g] * acc[2 * g] + acc[2 * g + 1] * acc[2 * g + 1];
#pragma unroll
        for (int m = 32; m > 0; m >>= 1) {
            s += __shfl_xor(s, m, 64);
            q += __shfl_xor(q, m, 64);
        }
        if (lane == 0) {
            tile[(g * 2 + 0) * 4 + wv] = s;
            tile[(g * 2 + 1) * 4 + wv] = q;
        }
    }
    __syncthreads();
    if (threadIdx.x < 10) {
        int g = threadIdx.x >> 1;
        int which = threadIdx.x & 1;
        float sum = tile[(g * 2 + which) * 4 + 0] + tile[(g * 2 + which) * 4 + 1] +
                    tile[(g * 2 + which) * 4 + 2] + tile[(g * 2 + which) * 4 + 3];
        atomicAdd(&stats1[(b * 5 + g) * 2 + which], sum);
    }
}

// ---------------- K2: finalize GN1 stats -> (mean, istd) --------------------------
__global__ void k2_fin1(const float* __restrict__ stats1, float* __restrict__ s1f) {
    int i = threadIdx.x;
    if (i < 20) {
        const float n = 2.f * WH;
        float s = stats1[2 * i], q = stats1[2 * i + 1];
        float m = s / n;
        float var = q / n - m * m;
        s1f[2 * i] = m;
        s1f[2 * i + 1] = rsqrtf(var + 1e-5f);
    }
}

// ---------------- K3: GN1+tanh+cumsum + LDS bilinear + stride-9 conv --------------
// Block: (b, 4 w-rows, 64 h-cols), 256 threads = 256 px. LDS: 4ch x 14r, PITCH 96.
// Pitch 96 == 0 mod 32: bank depends only on column (lane-consecutive) -> no
// conflicts from the per-lane-random bilinear row index.
__global__ __launch_bounds__(256, 4) void k3_sample(
    const float* __restrict__ xin, const float* __restrict__ off_buf,
    const float* __restrict__ s1f, const float* __restrict__ go_scale,
    const float* __restrict__ go_bias, const float* __restrict__ wdT2,
    const float* __restrict__ b_dsc, float* __restrict__ pre_out,
    float* __restrict__ stats2) {
    __shared__ float tile[4 * 14 * 96];   // 21,504 B

    const int b = blockIdx.z;
    const int w0 = blockIdx.y * 4;
    const int h0 = blockIdx.x * 64;
    const int lane = threadIdx.x & 63;
    const int wv = threadIdx.x >> 6;      // wave id = w-row index
    const int h = h0 + lane;
    const int w = w0 + wv;
    const int row0 = w0 - 5;
    const int col0 = h0 - 8;

    // offsets: GN1 + tanh on channels 0..8 -> cumsum
    float t9[9];
    size_t obase = (size_t)b * 10 * WH + (size_t)w * 256 + h;
#pragma unroll
    for (int c = 0; c < 9; ++c) {
        float v = off_buf[obase + (size_t)c * WH];
        int g = c >> 1;
        float mean = s1f[(b * 5 + g) * 2 + 0];
        float istd = s1f[(b * 5 + g) * 2 + 1];
        v = (v - mean) * istd * go_scale[c] + go_bias[c];
        t9[c] = tanhf(v);
    }
    float ycum[9];
    ycum[3] = t9[3];
    ycum[2] = ycum[3] + t9[2];
    ycum[1] = ycum[2] + t9[1];
    ycum[0] = ycum[1] + t9[0];
    ycum[4] = 0.f;
    ycum[5] = t9[5];
    ycum[6] = ycum[5] + t9[6];
    ycum[7] = ycum[6] + t9[7];
    ycum[8] = ycum[7] + t9[8];

    float acc[32];
#pragma unroll
    for (int o = 0; o < 32; ++o) acc[o] = 0.f;

    const float* xb = xin + (size_t)b * CC * WH;
    const float SC = 255.f / 256.f;

    const float4* wp = (const float4*)wdT2;
    float4 wc[8];
#pragma unroll
    for (int q = 0; q < 8; ++q) wc[q] = wp[q];
    wp += 8;

    for (int ch = 0; ch < 8; ++ch) {
        // stage 4 channels x 14 rows x 76 cols (replicate-clamped), float4 loads
        for (int t = threadIdx.x; t < 1064; t += 256) {
            int c = t / 266;              // 14*19
            int rem = t - c * 266;
            int r = rem / 19;
            int cf = rem - r * 19;
            int y = min(max(row0 + r, 0), 255);
            int g0 = col0 + (cf << 2);
            const float* src = xb + (size_t)(ch * 4 + c) * WH + y * 256;
            float4 val;
            if (g0 >= 0 && g0 <= 252) {
                val = *(const float4*)(src + g0);
            } else {
                val.x = src[min(max(g0, 0), 255)];
                val.y = src[min(max(g0 + 1, 0), 255)];
                val.z = src[min(max(g0 + 2, 0), 255)];
                val.w = src[min(max(g0 + 3, 0), 255)];
            }
            *(float4*)(tile + (c * 14 + r) * 96 + (cf << 2)) = val;
        }
        __syncthreads();

#pragma unroll
        for (int k = 0; k < 9; ++k) {
            float py = fminf(fmaxf(((float)w + ycum[k]) * SC, 0.f), 255.f);
            float pxc = fminf(fmaxf((float)(h + k - 4) * SC, 0.f), 255.f);
            float y0f = floorf(py), x0f = floorf(pxc);
            float wy = py - y0f, wx = pxc - x0f;
            int r0 = (int)y0f - row0;
            int r1 = min((int)y0f + 1, 255) - row0;
            int tc = (int)x0f - col0;
            float w00 = (1.f - wy) * (1.f - wx);
            float w01 = (1.f - wy) * wx;
            float w10 = wy * (1.f - wx);
            float w11 = wy * wx;
#pragma unroll
            for (int cl = 0; cl < 4; ++cl) {
                float4 wn[8];
#pragma unroll
                for (int q = 0; q < 8; ++q) wn[q] = wp[q];
                wp += 8;

                const float* p0 = tile + (cl * 14 + r0) * 96 + tc;
                const float* p1 = tile + (cl * 14 + r1) * 96 + tc;
                float v = fmaf(w00, p0[0],
                          fmaf(w01, p0[1], fmaf(w10, p1[0], w11 * p1[1])));
#pragma unroll
                for (int q = 0; q < 8; ++q) {
                    acc[q * 4 + 0] = fmaf(v, wc[q].x, acc[q * 4 + 0]);
                    acc[q * 4 + 1] = fmaf(v, wc[q].y, acc[q * 4 + 1]);
                    acc[q * 4 + 2] = fmaf(v, wc[q].z, acc[q * 4 + 2]);
                    acc[q * 4 + 3] = fmaf(v, wc[q].w, acc[q * 4 + 3]);
                }
#pragma unroll
                for (int q = 0; q < 8; ++q) wc[q] = wn[q];
            }
        }
        __syncthreads();
    }

    size_t pbase = (size_t)b * CC * WH + (size_t)w * 256 + h;
#pragma unroll
    for (int o = 0; o < 32; ++o) {
        acc[o] += b_dsc[o];
        pre_out[pbase + (size_t)o * WH] = acc[o];
    }

    // GN2 stats, block-reduced: group g covers channels {4g..4g+3}
#pragma unroll
    for (int g = 0; g < 8; ++g) {
        float s = acc[4 * g] + acc[4 * g + 1] + acc[4 * g + 2] + acc[4 * g + 3];
        float q = acc[4 * g] * acc[4 * g] + acc[4 * g + 1] * acc[4 * g + 1] +
                  acc[4 * g + 2] * acc[4 * g + 2] + acc[4 * g + 3] * acc[4 * g + 3];
#pragma unroll
        for (int m = 32; m > 0; m >>= 1) {
            s += __shfl_xor(s, m, 64);
            q += __shfl_xor(q, m, 64);
        }
        if (lane == 0) {
            tile[(g * 2 + 0) * 4 + wv] = s;
            tile[(g * 2 + 1) * 4 + wv] = q;
        }
    }
    __syncthreads();
    if (threadIdx.x < 16) {
        int g = threadIdx.x >> 1;
        int which = threadIdx.x & 1;
        float sum = tile[(g * 2 + which) * 4 + 0] + tile[(g * 2 + which) * 4 + 1] +
                    tile[(g * 2 + which) * 4 + 2] + tile[(g * 2 + which) * 4 + 3];
        atomicAdd(&stats2[(b * 8 + g) * 2 + which], sum);
    }
}

// ---------------- K4: finalize GN2 stats ------------------------------------------
__global__ void k4_fin2(const float* __restrict__ stats2, float* __restrict__ s2f) {
    int i = threadIdx.x;
    if (i < 32) {
        const float n = 4.f * WH;
        float s = stats2[2 * i], q = stats2[2 * i + 1];
        float m = s / n;
        float var = q / n - m * m;
        s2f[2 * i] = m;
        s2f[2 * i + 1] = rsqrtf(var + 1e-5f);
    }
}

// ---------------- K5: GN2 apply + ReLU, float4 (in-place on d_out) ----------------
__global__ __launch_bounds__(256) void k5_gn(float4* __restrict__ out,
                                             const float* __restrict__ s2f,
                                             const float* __restrict__ gs,
                                             const float* __restrict__ gb) {
    int idx = blockIdx.x * 256 + threadIdx.x;   // < 2097152
    int bo = idx >> 14;           // b*32 + o  (16384 float4 per channel-plane)
    int b = bo >> 5;
    int o = bo & 31;
    int g = o >> 2;
    float mean = s2f[(b * 8 + g) * 2 + 0];
    float istd = s2f[(b * 8 + g) * 2 + 1];
    float sc = gs[o] * istd;
    float bi = gb[o] - mean * sc;
    float4 v = out[idx];
    v.x = fmaxf(fmaf(v.x, sc, bi), 0.f);
    v.y = fmaxf(fmaf(v.y, sc, bi), 0.f);
    v.z = fmaxf(fmaf(v.z, sc, bi), 0.f);
    v.w = fmaxf(fmaf(v.w, sc, bi), 0.f);
    out[idx] = v;
}

extern "C" void kernel_launch(void* const* d_in, const int* in_sizes, int n_in,
                              void* d_out, int out_size, void* d_ws, size_t ws_size,
                              hipStream_t stream) {
    const float* x        = (const float*)d_in[0];
    const float* w_off    = (const float*)d_in[1];
    const float* b_off    = (const float*)d_in[2];
    const float* go_scale = (const float*)d_in[3];
    const float* go_bias  = (const float*)d_in[4];
    const float* w_dsc    = (const float*)d_in[5];
    const float* b_dsc    = (const float*)d_in[6];
    const float* gn_scale = (const float*)d_in[7];
    const float* gn_bias  = (const float*)d_in[8];
    float* out = (float*)d_out;

    float* ws      = (float*)d_ws;
    float* off_buf = ws;                              // 2,621,440
    float* wT1     = off_buf + (size_t)BB * 10 * WH;  // 3,856 (12 pad + align)
    float* wdT2    = wT1 + 3856;                      // 9,248 (32 pad)
    float* stats1  = wdT2 + 9248;                     // 40
    float* s1f     = stats1 + 40;                     // 40
    float* stats2  = s1f + 40;                        // 64
    float* s2f     = stats2 + 64;                     // 64

    k0_init<<<37, 256, 0, stream>>>(w_dsc, w_off, wT1, wdT2, stats1, stats2);
    k1_conv<<<dim3(2, 128, BB), 256, 0, stream>>>(x, wT1, b_off, off_buf, stats1);
    k2_fin1<<<1, 64, 0, stream>>>(stats1, s1f);
    k3_sample<<<dim3(4, 64, BB), 256, 0, stream>>>(x, off_buf, s1f, go_scale, go_bias,
                                                   wdT2, b_dsc, out, stats2);
    k4_fin2<<<1, 64, 0, stream>>>(stats2, s2f);
    k5_gn<<<8192, 256, 0, stream>>>((float4*)out, s2f, gn_scale, gn_bias);
}